// Round 2
// baseline (7305.907 us; speedup 1.0000x reference)
//
#include <hip/hip_runtime.h>
#include <math.h>

// Sizes (fixed by the problem)
#define BB   64
#define TT   128
#define HH   1024
#define DIN  2048
#define G4   4096
#define MALL 8192   // B*T
#define NANS 1000
#define HIDN 256

__device__ __forceinline__ float sigmoidf_(float x) { return 1.0f / (1.0f + expf(-x)); }

// ---------------------------------------------------------------------------
// K1: gates_x[m][n] = sum_k joint[m][k] * Wih1[n][k] + b1[n]
// joint = concat(data1, data2) along k (each 1024 wide). M=8192, K=2048, N=4096.
// 128x128 tile, BK=16, 8x8 micro-tile, 256 threads.
// ---------------------------------------------------------------------------
__global__ __launch_bounds__(256) void k1_gemm(
    const float* __restrict__ d1, const float* __restrict__ d2,
    const float* __restrict__ Wih1, const float* __restrict__ b1,
    float* __restrict__ gx)
{
  __shared__ float As[16][132];
  __shared__ float Bs[16][132];
  const int m0 = blockIdx.y * 128;
  const int n0 = blockIdx.x * 128;
  const int t  = threadIdx.x;
  const int tx = t & 15, ty = t >> 4;
  float acc[8][8] = {};
  for (int k0 = 0; k0 < DIN; k0 += 16) {
    #pragma unroll
    for (int i = 0; i < 2; i++) {          // A tile: 128 rows x 16 k = 512 float4
      int idx = t + i * 256;
      int r = idx >> 2, kv = idx & 3;
      int gk = k0 + kv * 4;
      const float* src = (gk < 1024) ? (d1 + (size_t)(m0 + r) * 1024 + gk)
                                     : (d2 + (size_t)(m0 + r) * 1024 + (gk - 1024));
      float4 v = *(const float4*)src;
      As[kv*4+0][r] = v.x; As[kv*4+1][r] = v.y; As[kv*4+2][r] = v.z; As[kv*4+3][r] = v.w;
    }
    #pragma unroll
    for (int i = 0; i < 2; i++) {          // B tile: Wih1 rows n0..n0+127
      int idx = t + i * 256;
      int r = idx >> 2, kv = idx & 3;
      float4 v = *(const float4*)(Wih1 + (size_t)(n0 + r) * 2048 + k0 + kv * 4);
      Bs[kv*4+0][r] = v.x; Bs[kv*4+1][r] = v.y; Bs[kv*4+2][r] = v.z; Bs[kv*4+3][r] = v.w;
    }
    __syncthreads();
    #pragma unroll
    for (int k = 0; k < 16; k++) {
      float a[8], b[8];
      *(float4*)&a[0] = *(const float4*)&As[k][ty*8];
      *(float4*)&a[4] = *(const float4*)&As[k][ty*8+4];
      *(float4*)&b[0] = *(const float4*)&Bs[k][tx*8];
      *(float4*)&b[4] = *(const float4*)&Bs[k][tx*8+4];
      #pragma unroll
      for (int i = 0; i < 8; i++)
        #pragma unroll
        for (int j = 0; j < 8; j++)
          acc[i][j] += a[i] * b[j];
    }
    __syncthreads();
  }
  #pragma unroll
  for (int i = 0; i < 8; i++) {
    int m = m0 + ty * 8 + i;
    #pragma unroll
    for (int jv = 0; jv < 2; jv++) {
      int n = n0 + tx * 8 + jv * 4;
      float4 o;
      o.x = acc[i][jv*4+0] + b1[n+0];
      o.y = acc[i][jv*4+1] + b1[n+1];
      o.z = acc[i][jv*4+2] + b1[n+2];
      o.w = acc[i][jv*4+3] + b1[n+3];
      *(float4*)(gx + (size_t)m * 4096 + n) = o;
    }
  }
}

// ---------------------------------------------------------------------------
// init: zero hcat (64x2048) + c1 (64x1024) + c2 (64x1024), contiguous 262144 floats
// ---------------------------------------------------------------------------
__global__ __launch_bounds__(256) void init_state(float* __restrict__ hcat)
{
  int i = blockIdx.x * 256 + threadIdx.x;   // grid 256 -> 65536 threads x float4
  *(float4*)(hcat + (size_t)i * 4) = make_float4(0.f, 0.f, 0.f, 0.f);
}

// ---------------------------------------------------------------------------
// stepA_gemm: partials of h1_prev @ Whh1^T. grid (64 ntiles, 16 ksplits).
// Block: M=64 (all batch), 64 gate-cols = {i,f,g,o} x 16 h-cols at j0, K=64 slice.
// part[(ks*64+m)*4096 + gate*1024 + j]
// NOTE grid.x MUST be 64: 64 tiles x 16 h-cols = 1024 h-cols per gate.
// (Round-1 bug: grid.x=16 left 75% of `part` at 0xAA poison ~= -3e-13, i.e.
//  silently dropped the recurrent contribution for those units -> absmax 3.8e-5.)
// ---------------------------------------------------------------------------
__global__ __launch_bounds__(256) void stepA_gemm(
    const float* __restrict__ hcat, const float* __restrict__ Whh1,
    float* __restrict__ part)
{
  __shared__ float As[16][68];
  __shared__ float Bs[16][68];
  const int j0 = blockIdx.x * 16;
  const int kbase = blockIdx.y * 64;
  const int t = threadIdx.x;
  const int tx = t & 15, ty = t >> 4;
  const int r = t >> 2, kv = t & 3;
  const int nr = ((r >> 4) << 10) + j0 + (r & 15);   // gate-scattered weight row
  float acc[4][4] = {};
  for (int kc = 0; kc < 64; kc += 16) {
    int k0 = kbase + kc;
    { float4 v = *(const float4*)(hcat + (size_t)r * 2048 + k0 + kv * 4);
      As[kv*4+0][r] = v.x; As[kv*4+1][r] = v.y; As[kv*4+2][r] = v.z; As[kv*4+3][r] = v.w; }
    { float4 v = *(const float4*)(Whh1 + (size_t)nr * 1024 + k0 + kv * 4);
      Bs[kv*4+0][r] = v.x; Bs[kv*4+1][r] = v.y; Bs[kv*4+2][r] = v.z; Bs[kv*4+3][r] = v.w; }
    __syncthreads();
    #pragma unroll
    for (int k = 0; k < 16; k++) {
      float a[4], b[4];
      *(float4*)a = *(const float4*)&As[k][ty*4];
      *(float4*)b = *(const float4*)&Bs[k][tx*4];
      #pragma unroll
      for (int i = 0; i < 4; i++)
        #pragma unroll
        for (int j = 0; j < 4; j++)
          acc[i][j] += a[i] * b[j];
    }
    __syncthreads();
  }
  const int gate = tx >> 2;
  const int jc = (tx & 3) * 4;
  #pragma unroll
  for (int i = 0; i < 4; i++) {
    int m = ty * 4 + i;
    *(float4*)(part + (size_t)(blockIdx.y * 64 + m) * 4096 + (gate << 10) + j0 + jc)
        = make_float4(acc[i][0], acc[i][1], acc[i][2], acc[i][3]);
  }
}

// ---------------------------------------------------------------------------
// stepA_elem: gates = gx[:,t,:] + sum_ks part; LSTM cell 1; h1 -> hcat[:, :1024]
// ---------------------------------------------------------------------------
__global__ __launch_bounds__(256) void stepA_elem(
    const float* __restrict__ part, const float* __restrict__ gx, int t,
    float* __restrict__ hcat, float* __restrict__ c1)
{
  int idx = blockIdx.x * 256 + threadIdx.x;  // 65536
  int m = idx >> 10, j = idx & 1023;
  const float* g = gx + (size_t)(m * TT + t) * 4096 + j;
  float s0 = g[0], s1 = g[1024], s2 = g[2048], s3 = g[3072];
  #pragma unroll
  for (int ks = 0; ks < 16; ks++) {
    const float* p = part + (size_t)(ks * 64 + m) * 4096 + j;
    s0 += p[0]; s1 += p[1024]; s2 += p[2048]; s3 += p[3072];
  }
  float i_ = sigmoidf_(s0), f_ = sigmoidf_(s1), g_ = tanhf(s2), o_ = sigmoidf_(s3);
  float c = f_ * c1[idx] + i_ * g_;
  c1[idx] = c;
  hcat[(size_t)m * 2048 + j] = o_ * tanhf(c);
}

// ---------------------------------------------------------------------------
// stepB_gemm: partials of [h1|h2] @ [Wih2;Whh2]^T. grid (64 ntiles, 16 ksplits of 128).
// ---------------------------------------------------------------------------
__global__ __launch_bounds__(256) void stepB_gemm(
    const float* __restrict__ hcat, const float* __restrict__ Wih2,
    const float* __restrict__ Whh2, float* __restrict__ part)
{
  __shared__ float As[16][68];
  __shared__ float Bs[16][68];
  const int j0 = blockIdx.x * 16;
  const int kbase = blockIdx.y * 128;
  const float* W = (kbase < 1024) ? Wih2 : Whh2;
  const int koff = kbase & 1023;
  const int t = threadIdx.x;
  const int tx = t & 15, ty = t >> 4;
  const int r = t >> 2, kv = t & 3;
  const int nr = ((r >> 4) << 10) + j0 + (r & 15);
  float acc[4][4] = {};
  for (int kc = 0; kc < 128; kc += 16) {
    { float4 v = *(const float4*)(hcat + (size_t)r * 2048 + kbase + kc + kv * 4);
      As[kv*4+0][r] = v.x; As[kv*4+1][r] = v.y; As[kv*4+2][r] = v.z; As[kv*4+3][r] = v.w; }
    { float4 v = *(const float4*)(W + (size_t)nr * 1024 + koff + kc + kv * 4);
      Bs[kv*4+0][r] = v.x; Bs[kv*4+1][r] = v.y; Bs[kv*4+2][r] = v.z; Bs[kv*4+3][r] = v.w; }
    __syncthreads();
    #pragma unroll
    for (int k = 0; k < 16; k++) {
      float a[4], b[4];
      *(float4*)a = *(const float4*)&As[k][ty*4];
      *(float4*)b = *(const float4*)&Bs[k][tx*4];
      #pragma unroll
      for (int i = 0; i < 4; i++)
        #pragma unroll
        for (int j = 0; j < 4; j++)
          acc[i][j] += a[i] * b[j];
    }
    __syncthreads();
  }
  const int gate = tx >> 2;
  const int jc = (tx & 3) * 4;
  #pragma unroll
  for (int i = 0; i < 4; i++) {
    int m = ty * 4 + i;
    *(float4*)(part + (size_t)(blockIdx.y * 64 + m) * 4096 + (gate << 10) + j0 + jc)
        = make_float4(acc[i][0], acc[i][1], acc[i][2], acc[i][3]);
  }
}

// ---------------------------------------------------------------------------
// stepB_elem: gates2 = b2 + sum_ks part; cell 2; h2 -> hcat[:,1024:]; out_t = h1+h2
// ---------------------------------------------------------------------------
__global__ __launch_bounds__(256) void stepB_elem(
    const float* __restrict__ part, const float* __restrict__ b2, int t,
    float* __restrict__ hcat, float* __restrict__ c2, float* __restrict__ lstm_out)
{
  int idx = blockIdx.x * 256 + threadIdx.x;
  int m = idx >> 10, j = idx & 1023;
  float s0 = b2[j], s1 = b2[1024 + j], s2 = b2[2048 + j], s3 = b2[3072 + j];
  #pragma unroll
  for (int ks = 0; ks < 16; ks++) {
    const float* p = part + (size_t)(ks * 64 + m) * 4096 + j;
    s0 += p[0]; s1 += p[1024]; s2 += p[2048]; s3 += p[3072];
  }
  float i_ = sigmoidf_(s0), f_ = sigmoidf_(s1), g_ = tanhf(s2), o_ = sigmoidf_(s3);
  float c = f_ * c2[idx] + i_ * g_;
  c2[idx] = c;
  float h2v = o_ * tanhf(c);
  hcat[(size_t)m * 2048 + 1024 + j] = h2v;
  lstm_out[(size_t)(m * TT + t) * 1024 + j] = hcat[(size_t)m * 2048 + j] + h2v;
}

// ---------------------------------------------------------------------------
// mlp1: hid = relu(lstm_out @ Wp1 + bp1). [8192,1024]x[1024,256].
// 128x64 tile, 8x4 micro. Wp1 is [K][N] (n-contiguous). grid (4, 64).
// ---------------------------------------------------------------------------
__global__ __launch_bounds__(256) void mlp1_gemm(
    const float* __restrict__ lo, const float* __restrict__ Wp1,
    const float* __restrict__ bp1, float* __restrict__ hid)
{
  __shared__ float As[16][132];
  __shared__ float Bs[16][68];
  const int n0 = blockIdx.x * 64, m0 = blockIdx.y * 128;
  const int t = threadIdx.x, tx = t & 15, ty = t >> 4;
  float acc[8][4] = {};
  for (int k0 = 0; k0 < 1024; k0 += 16) {
    #pragma unroll
    for (int i = 0; i < 2; i++) {
      int idx = t + i * 256;
      int r = idx >> 2, kv = idx & 3;
      float4 v = *(const float4*)(lo + (size_t)(m0 + r) * 1024 + k0 + kv * 4);
      As[kv*4+0][r] = v.x; As[kv*4+1][r] = v.y; As[kv*4+2][r] = v.z; As[kv*4+3][r] = v.w;
    }
    { int k = t >> 4, nv = t & 15;
      float4 v = *(const float4*)(Wp1 + (size_t)(k0 + k) * 256 + n0 + nv * 4);
      *(float4*)&Bs[k][nv*4] = v; }
    __syncthreads();
    #pragma unroll
    for (int k = 0; k < 16; k++) {
      float a[8], b[4];
      *(float4*)&a[0] = *(const float4*)&As[k][ty*8];
      *(float4*)&a[4] = *(const float4*)&As[k][ty*8+4];
      *(float4*)b = *(const float4*)&Bs[k][tx*4];
      #pragma unroll
      for (int i = 0; i < 8; i++)
        #pragma unroll
        for (int j = 0; j < 4; j++)
          acc[i][j] += a[i] * b[j];
    }
    __syncthreads();
  }
  #pragma unroll
  for (int i = 0; i < 8; i++) {
    int m = m0 + ty * 8 + i;
    int n = n0 + tx * 4;
    float4 o;
    o.x = fmaxf(acc[i][0] + bp1[n+0], 0.f);
    o.y = fmaxf(acc[i][1] + bp1[n+1], 0.f);
    o.z = fmaxf(acc[i][2] + bp1[n+2], 0.f);
    o.w = fmaxf(acc[i][3] + bp1[n+3], 0.f);
    *(float4*)(hid + (size_t)m * 256 + n) = o;
  }
}

// ---------------------------------------------------------------------------
// logits: out = hid @ Wp2 + bp2. [8192,256]x[256,1000]. 128x128 tile, 8x8 micro.
// N ragged (1000): guarded loads/stores on the last n-tile. grid (8, 64).
// ---------------------------------------------------------------------------
__global__ __launch_bounds__(256) void logits_gemm(
    const float* __restrict__ hid, const float* __restrict__ Wp2,
    const float* __restrict__ bp2, float* __restrict__ out)
{
  __shared__ float As[16][132];
  __shared__ float Bs[16][132];
  const int n0 = blockIdx.x * 128, m0 = blockIdx.y * 128;
  const int t = threadIdx.x, tx = t & 15, ty = t >> 4;
  float acc[8][8] = {};
  for (int k0 = 0; k0 < 256; k0 += 16) {
    #pragma unroll
    for (int i = 0; i < 2; i++) {
      int idx = t + i * 256;
      int r = idx >> 2, kv = idx & 3;
      float4 v = *(const float4*)(hid + (size_t)(m0 + r) * 256 + k0 + kv * 4);
      As[kv*4+0][r] = v.x; As[kv*4+1][r] = v.y; As[kv*4+2][r] = v.z; As[kv*4+3][r] = v.w;
    }
    #pragma unroll
    for (int i = 0; i < 2; i++) {
      int idx = t + i * 256;
      int k = idx >> 5, nv = idx & 31;
      int n = n0 + nv * 4;
      float4 v;
      if (n + 3 < NANS) {
        v = *(const float4*)(Wp2 + (size_t)(k0 + k) * NANS + n);
      } else {
        v.x = (n + 0 < NANS) ? Wp2[(size_t)(k0 + k) * NANS + n + 0] : 0.f;
        v.y = (n + 1 < NANS) ? Wp2[(size_t)(k0 + k) * NANS + n + 1] : 0.f;
        v.z = (n + 2 < NANS) ? Wp2[(size_t)(k0 + k) * NANS + n + 2] : 0.f;
        v.w = (n + 3 < NANS) ? Wp2[(size_t)(k0 + k) * NANS + n + 3] : 0.f;
      }
      *(float4*)&Bs[k][nv*4] = v;
    }
    __syncthreads();
    #pragma unroll
    for (int k = 0; k < 16; k++) {
      float a[8], b[8];
      *(float4*)&a[0] = *(const float4*)&As[k][ty*8];
      *(float4*)&a[4] = *(const float4*)&As[k][ty*8+4];
      *(float4*)&b[0] = *(const float4*)&Bs[k][tx*8];
      *(float4*)&b[4] = *(const float4*)&Bs[k][tx*8+4];
      #pragma unroll
      for (int i = 0; i < 8; i++)
        #pragma unroll
        for (int j = 0; j < 8; j++)
          acc[i][j] += a[i] * b[j];
    }
    __syncthreads();
  }
  #pragma unroll
  for (int i = 0; i < 8; i++) {
    int m = m0 + ty * 8 + i;
    #pragma unroll
    for (int jv = 0; jv < 2; jv++) {
      int n = n0 + tx * 8 + jv * 4;
      if (n + 3 < NANS) {
        float4 o;
        o.x = acc[i][jv*4+0] + bp2[n+0];
        o.y = acc[i][jv*4+1] + bp2[n+1];
        o.z = acc[i][jv*4+2] + bp2[n+2];
        o.w = acc[i][jv*4+3] + bp2[n+3];
        *(float4*)(out + (size_t)m * NANS + n) = o;
      } else {
        #pragma unroll
        for (int jj = 0; jj < 4; jj++)
          if (n + jj < NANS)
            out[(size_t)m * NANS + n + jj] = acc[i][jv*4+jj] + bp2[n+jj];
      }
    }
  }
}

// ---------------------------------------------------------------------------
// softmax over last dim (1000), in place on out. One block per row.
// ---------------------------------------------------------------------------
__global__ __launch_bounds__(256) void softmax_k(float* __restrict__ out)
{
  __shared__ float smax[4];
  __shared__ float ssum[4];
  const int m = blockIdx.x;
  const int t = threadIdx.x;
  const int lane = t & 63, wid = t >> 6;
  const bool act = (t < 250);                  // 250*4 = 1000
  float x[4] = {0.f, 0.f, 0.f, 0.f};
  if (act) *(float4*)x = *(const float4*)(out + (size_t)m * NANS + t * 4);
  float v = act ? fmaxf(fmaxf(x[0], x[1]), fmaxf(x[2], x[3])) : -1e30f;
  #pragma unroll
  for (int o = 32; o > 0; o >>= 1) v = fmaxf(v, __shfl_down(v, o));
  if (lane == 0) smax[wid] = v;
  __syncthreads();
  const float mx = fmaxf(fmaxf(smax[0], smax[1]), fmaxf(smax[2], smax[3]));
  float e[4] = {0.f, 0.f, 0.f, 0.f};
  float s = 0.f;
  if (act) {
    e[0] = expf(x[0] - mx); e[1] = expf(x[1] - mx);
    e[2] = expf(x[2] - mx); e[3] = expf(x[3] - mx);
    s = (e[0] + e[1]) + (e[2] + e[3]);
  }
  #pragma unroll
  for (int o = 32; o > 0; o >>= 1) s += __shfl_down(s, o);
  if (lane == 0) ssum[wid] = s;
  __syncthreads();
  const float inv = 1.0f / (((ssum[0] + ssum[1]) + (ssum[2] + ssum[3])));
  if (act) {
    float4 o4 = make_float4(e[0] * inv, e[1] * inv, e[2] * inv, e[3] * inv);
    *(float4*)(out + (size_t)m * NANS + t * 4) = o4;
  }
}

// ---------------------------------------------------------------------------
extern "C" void kernel_launch(void* const* d_in, const int* in_sizes, int n_in,
                              void* d_out, int out_size, void* d_ws, size_t ws_size,
                              hipStream_t stream)
{
  const float* d1   = (const float*)d_in[0];
  const float* d2   = (const float*)d_in[1];
  const float* Wih1 = (const float*)d_in[2];
  const float* Whh1 = (const float*)d_in[3];
  const float* b1   = (const float*)d_in[4];
  const float* Wih2 = (const float*)d_in[5];
  const float* Whh2 = (const float*)d_in[6];
  const float* b2   = (const float*)d_in[7];
  const float* Wp1  = (const float*)d_in[8];
  const float* bp1  = (const float*)d_in[9];
  const float* Wp2  = (const float*)d_in[10];
  const float* bp2  = (const float*)d_in[11];
  float* out = (float*)d_out;

  // workspace layout (floats)
  float* ws   = (float*)d_ws;
  float* gx   = ws;                          // 8192*4096   = 33,554,432
  float* part = gx + (size_t)33554432;       // 16*64*4096  =  4,194,304
  float* hcat = part + 4194304;              // 64*2048     =    131,072  (h1|h2)
  float* c1   = hcat + 131072;               // 64*1024     =     65,536
  float* c2   = c1 + 65536;                  // 64*1024     =     65,536
  float* lo   = c2 + 65536;                  // 8192*1024   =  8,388,608
  float* hid  = lo + 8388608;                // 8192*256    =  2,097,152
  // total 48,496,640 floats ~= 185 MiB
  if (ws_size < (size_t)48496640 * sizeof(float)) return;

  k1_gemm<<<dim3(32, 64), 256, 0, stream>>>(d1, d2, Wih1, b1, gx);
  init_state<<<256, 256, 0, stream>>>(hcat);

  for (int t = 0; t < TT; t++) {
    stepA_gemm<<<dim3(64, 16), 256, 0, stream>>>(hcat, Whh1, part);
    stepA_elem<<<256, 256, 0, stream>>>(part, gx, t, hcat, c1);
    stepB_gemm<<<dim3(64, 16), 256, 0, stream>>>(hcat, Wih2, Whh2, part);
    stepB_elem<<<256, 256, 0, stream>>>(part, b2, t, hcat, c2, lo);
  }

  mlp1_gemm<<<dim3(4, 64), 256, 0, stream>>>(lo, Wp1, bp1, hid);
  logits_gemm<<<dim3(8, 64), 256, 0, stream>>>(hid, Wp2, bp2, out);
  softmax_k<<<8192, 256, 0, stream>>>(out);
}

// Round 3
// 3180.460 us; speedup vs baseline: 2.2971x; 2.2971x over previous
//
#include <hip/hip_runtime.h>
#include <math.h>

#define BB   64
#define TT   128
#define HH   1024
#define DIN  2048
#define G4   4096
#define MALL 8192   // B*T
#define NANS 1000

typedef __attribute__((ext_vector_type(8))) short bf16x8;
typedef __attribute__((ext_vector_type(4))) float f32x4;

__device__ __forceinline__ float sigmoidf_(float x) { return 1.0f / (1.0f + expf(-x)); }

__device__ __forceinline__ unsigned short f2bf(float f) {
  unsigned u = __float_as_uint(f);
  u = (u + 0x7fff + ((u >> 16) & 1)) >> 16;   // RNE
  return (unsigned short)u;
}
__device__ __forceinline__ float bf2f(unsigned short h) {
  return __uint_as_float(((unsigned)h) << 16);
}
__device__ __forceinline__ f32x4 mfma16(bf16x8 a, bf16x8 b, f32x4 c) {
  return __builtin_amdgcn_mfma_f32_16x16x32_bf16(a, b, c, 0, 0, 0);
}

// ---------------------------------------------------------------------------
// concat_cast: o[row][col] bf16 <- col<half ? a[row][col] : b[row][col-half]
// rshift = log2(row width). Used for joint (d1|d2) and W2cat (Wih2|Whh2).
// ---------------------------------------------------------------------------
__global__ __launch_bounds__(256) void concat_cast(
    const float* __restrict__ a, const float* __restrict__ b,
    unsigned short* __restrict__ o, int rshift, long total)
{
  long idx = ((long)blockIdx.x * 256 + threadIdx.x) * 4;
  if (idx >= total) return;
  int row = (int)(idx >> rshift);
  int col = (int)(idx & ((1L << rshift) - 1));
  int half = 1 << (rshift - 1);
  const float* s = (col < half) ? (a + (size_t)row * half + col)
                                : (b + (size_t)row * half + col - half);
  float4 v = *(const float4*)s;
  ushort4 ov;
  ov.x = f2bf(v.x); ov.y = f2bf(v.y); ov.z = f2bf(v.z); ov.w = f2bf(v.w);
  *(ushort4*)(o + idx) = ov;
}

__global__ __launch_bounds__(256) void cast_bf16(
    const float* __restrict__ s, unsigned short* __restrict__ o, long n)
{
  long idx = ((long)blockIdx.x * 256 + threadIdx.x) * 4;
  if (idx >= n) return;
  float4 v = *(const float4*)(s + idx);
  ushort4 ov;
  ov.x = f2bf(v.x); ov.y = f2bf(v.y); ov.z = f2bf(v.z); ov.w = f2bf(v.w);
  *(ushort4*)(o + idx) = ov;
}

// Wp1t[n][k] = Wp1[k][n]  (Wp1: [1024][256] fp32 -> [256][1024] bf16)
__global__ __launch_bounds__(256) void cvt_wp1(
    const float* __restrict__ Wp1, unsigned short* __restrict__ o)
{
  int idx = blockIdx.x * 256 + threadIdx.x;    // 262144
  int n = idx >> 10, k = idx & 1023;
  o[idx] = f2bf(Wp1[(size_t)k * 256 + n]);
}

// Wp2t[n][k] = Wp2[k][n], n padded 1000->1024 with zeros ([256][1000] -> [1024][256])
__global__ __launch_bounds__(256) void cvt_wp2(
    const float* __restrict__ Wp2, unsigned short* __restrict__ o)
{
  int idx = blockIdx.x * 256 + threadIdx.x;    // 262144
  int n = idx >> 8, k = idx & 255;
  o[idx] = f2bf(n < NANS ? Wp2[(size_t)k * NANS + n] : 0.f);
}

__global__ __launch_bounds__(256) void zero_f4(float4* __restrict__ p)
{
  p[blockIdx.x * 256 + threadIdx.x] = make_float4(0.f, 0.f, 0.f, 0.f);
}

// ---------------------------------------------------------------------------
// Templated bf16 MFMA GEMM: C[m][n] = sum_k A[m][k] * W[n][k] (+bias) (relu)
// 128x128 tile, BK=64, 256 thr = 4 waves (2x2 of 64x64), 16x16x32 MFMA.
// PERM (k1 only): output row permuted b*T+t -> t*64+b so the step kernels read
// one contiguous slab per t. LDS rows padded to 72 elems -> conflict-free-ish
// ds_read_b128 fragments.
// ---------------------------------------------------------------------------
template<int OUT_BF16, int RELU, int PERM>
__global__ __launch_bounds__(256) void mfma_gemm(
    const unsigned short* __restrict__ A,   // [M][K] bf16
    const unsigned short* __restrict__ W,   // [N][K] bf16
    const float* __restrict__ bias,         // [nvalid]
    void* __restrict__ Cout,
    int M, int N, int K, int ldc, int nvalid)
{
  __shared__ __align__(16) unsigned short As[128 * 72];
  __shared__ __align__(16) unsigned short Bs[128 * 72];
  const int t = threadIdx.x;
  const int n0 = blockIdx.x * 128, m0 = blockIdx.y * 128;
  const int w = t >> 6, lane = t & 63, lr = lane & 15, q = lane >> 4;
  const int wn = (w & 1) * 64, wm = (w >> 1) * 64;
  f32x4 acc[4][4] = {};
  for (int k0 = 0; k0 < K; k0 += 64) {
    #pragma unroll
    for (int s = 0; s < 4; s++) {          // fully-coalesced staging
      int ci = s * 256 + t;                // 1024 chunks of 16B
      int row = ci >> 3, c = ci & 7;
      bf16x8 va = *(const bf16x8*)(A + (size_t)(m0 + row) * K + k0 + c * 8);
      *(bf16x8*)(As + row * 72 + c * 8) = va;
      bf16x8 vb = *(const bf16x8*)(W + (size_t)(n0 + row) * K + k0 + c * 8);
      *(bf16x8*)(Bs + row * 72 + c * 8) = vb;
    }
    __syncthreads();
    #pragma unroll
    for (int kk = 0; kk < 2; kk++) {
      bf16x8 a[4], b[4];
      #pragma unroll
      for (int mt = 0; mt < 4; mt++)
        a[mt] = *(const bf16x8*)(As + (wm + mt * 16 + lr) * 72 + kk * 32 + q * 8);
      #pragma unroll
      for (int nt = 0; nt < 4; nt++)
        b[nt] = *(const bf16x8*)(Bs + (wn + nt * 16 + lr) * 72 + kk * 32 + q * 8);
      #pragma unroll
      for (int mt = 0; mt < 4; mt++)
        #pragma unroll
        for (int nt = 0; nt < 4; nt++)
          acc[mt][nt] = mfma16(a[mt], b[nt], acc[mt][nt]);
    }
    __syncthreads();
  }
  #pragma unroll
  for (int mt = 0; mt < 4; mt++)
    #pragma unroll
    for (int nt = 0; nt < 4; nt++)
      #pragma unroll
      for (int r = 0; r < 4; r++) {
        int row = m0 + wm + mt * 16 + q * 4 + r;
        int col = n0 + wn + nt * 16 + lr;
        if (col < nvalid) {
          float v = acc[mt][nt][r] + bias[col];
          if (RELU) v = fmaxf(v, 0.f);
          if (PERM) row = ((row & 127) << 6) | (row >> 7);
          if (OUT_BF16)
            ((unsigned short*)Cout)[(size_t)row * ldc + col] = f2bf(v);
          else
            ((float*)Cout)[(size_t)row * ldc + col] = v;
        }
      }
}

// ---------------------------------------------------------------------------
// lstm_stepA: gates1 = h1_prev @ Whh1^T + gx[t]; cell1; h1 -> hcur[:, :1024].
// 256 blocks, block owns 4 hidden units (16 gate-cols). M=64, N=16, K=1024.
// 4 waves split K (256 each), LDS reduction, then 256-thread cell phase.
// ---------------------------------------------------------------------------
__global__ __launch_bounds__(256) void lstm_stepA(
    const unsigned short* __restrict__ hprev,   // [64][2048], h1_{t-1} in [0:1024]
    const unsigned short* __restrict__ Wb,      // Whh1b [4096][1024]
    const unsigned short* __restrict__ gxb,     // [T*64][4096] bf16 (t-major)
    int tstep,
    unsigned short* hcur,                       // h1_t -> [0:1024]
    float* __restrict__ c1)
{
  __shared__ float red[4][64][17];
  const int t = threadIdx.x;
  const int w = t >> 6, lane = t & 63, lr = lane & 15, q = lane >> 4;
  const int j0 = blockIdx.x * 4;
  {
    const int g = lr >> 2, u0 = lr & 3;
    const unsigned short* wp = Wb + (size_t)(g * 1024 + j0 + u0) * 1024;
    f32x4 acc[4] = {};
    const int kb = w * 256;
    #pragma unroll
    for (int ks = 0; ks < 8; ks++) {
      int k = kb + ks * 32 + q * 8;
      bf16x8 bfrag = *(const bf16x8*)(wp + k);
      #pragma unroll
      for (int mt = 0; mt < 4; mt++) {
        bf16x8 afrag = *(const bf16x8*)(hprev + (size_t)(mt * 16 + lr) * 2048 + k);
        acc[mt] = mfma16(afrag, bfrag, acc[mt]);
      }
    }
    #pragma unroll
    for (int mt = 0; mt < 4; mt++)
      #pragma unroll
      for (int r = 0; r < 4; r++)
        red[w][mt * 16 + q * 4 + r][lr] = acc[mt][r];
  }
  __syncthreads();
  const int m = t >> 2, u = t & 3;
  float s[4];
  #pragma unroll
  for (int g = 0; g < 4; g++)
    s[g] = red[0][m][g * 4 + u] + red[1][m][g * 4 + u]
         + red[2][m][g * 4 + u] + red[3][m][g * 4 + u];
  const unsigned short* gp = gxb + (size_t)((tstep << 6) + m) * 4096 + j0 + u;
  s[0] += bf2f(gp[0]); s[1] += bf2f(gp[1024]);
  s[2] += bf2f(gp[2048]); s[3] += bf2f(gp[3072]);
  const int ju = j0 + u;
  float i_ = sigmoidf_(s[0]), f_ = sigmoidf_(s[1]);
  float g_ = tanhf(s[2]), o_ = sigmoidf_(s[3]);
  float c = f_ * c1[m * 1024 + ju] + i_ * g_;
  c1[m * 1024 + ju] = c;
  hcur[(size_t)m * 2048 + ju] = f2bf(o_ * tanhf(c));
}

// ---------------------------------------------------------------------------
// lstm_stepB: gates2 = [h1_t | h2_{t-1}] @ [Wih2|Whh2]^T + b2; cell2;
// h2 -> hcur[:,1024:]; lstm_out[t] = h1+h2 (bf16). K=2048; k<1024 reads hcur
// (h1_t), k>=1024 reads hprev (h2_{t-1}) -- wave-uniform split (w<2 vs w>=2).
// ---------------------------------------------------------------------------
__global__ __launch_bounds__(256) void lstm_stepB(
    const unsigned short* __restrict__ hprev,
    unsigned short* hcur,
    const unsigned short* __restrict__ W2,      // [4096][2048]
    const float* __restrict__ b2,
    int tstep,
    float* __restrict__ c2,
    unsigned short* __restrict__ lob)
{
  __shared__ float red[4][64][17];
  const int t = threadIdx.x;
  const int w = t >> 6, lane = t & 63, lr = lane & 15, q = lane >> 4;
  const int j0 = blockIdx.x * 4;
  {
    const int g = lr >> 2, u0 = lr & 3;
    const unsigned short* wp = W2 + (size_t)(g * 1024 + j0 + u0) * 2048;
    f32x4 acc[4] = {};
    const int kb = w * 512;
    #pragma unroll
    for (int ks = 0; ks < 16; ks++) {
      int k = kb + ks * 32 + q * 8;
      bf16x8 bfrag = *(const bf16x8*)(wp + k);
      const unsigned short* hsrc = (k < 1024) ? hcur : hprev;
      #pragma unroll
      for (int mt = 0; mt < 4; mt++) {
        bf16x8 afrag = *(const bf16x8*)(hsrc + (size_t)(mt * 16 + lr) * 2048 + k);
        acc[mt] = mfma16(afrag, bfrag, acc[mt]);
      }
    }
    #pragma unroll
    for (int mt = 0; mt < 4; mt++)
      #pragma unroll
      for (int r = 0; r < 4; r++)
        red[w][mt * 16 + q * 4 + r][lr] = acc[mt][r];
  }
  __syncthreads();
  const int m = t >> 2, u = t & 3;
  const int ju = j0 + u;
  float s[4];
  #pragma unroll
  for (int g = 0; g < 4; g++)
    s[g] = red[0][m][g * 4 + u] + red[1][m][g * 4 + u]
         + red[2][m][g * 4 + u] + red[3][m][g * 4 + u]
         + b2[g * 1024 + ju];
  float i_ = sigmoidf_(s[0]), f_ = sigmoidf_(s[1]);
  float g_ = tanhf(s[2]), o_ = sigmoidf_(s[3]);
  float c = f_ * c2[m * 1024 + ju] + i_ * g_;
  c2[m * 1024 + ju] = c;
  float h2v = o_ * tanhf(c);
  hcur[(size_t)m * 2048 + 1024 + ju] = f2bf(h2v);
  float h1v = bf2f(hcur[(size_t)m * 2048 + ju]);
  lob[(size_t)((m << 7) + tstep) * 1024 + ju] = f2bf(h1v + h2v);
}

// ---------------------------------------------------------------------------
// softmax over last dim (1000), in place. One block per row.
// ---------------------------------------------------------------------------
__global__ __launch_bounds__(256) void softmax_k(float* __restrict__ out)
{
  __shared__ float smax[4];
  __shared__ float ssum[4];
  const int m = blockIdx.x;
  const int t = threadIdx.x;
  const int lane = t & 63, wid = t >> 6;
  const bool act = (t < 250);
  float x[4] = {0.f, 0.f, 0.f, 0.f};
  if (act) *(float4*)x = *(const float4*)(out + (size_t)m * NANS + t * 4);
  float v = act ? fmaxf(fmaxf(x[0], x[1]), fmaxf(x[2], x[3])) : -1e30f;
  #pragma unroll
  for (int o = 32; o > 0; o >>= 1) v = fmaxf(v, __shfl_down(v, o));
  if (lane == 0) smax[wid] = v;
  __syncthreads();
  const float mx = fmaxf(fmaxf(smax[0], smax[1]), fmaxf(smax[2], smax[3]));
  float e[4] = {0.f, 0.f, 0.f, 0.f};
  float s = 0.f;
  if (act) {
    e[0] = expf(x[0] - mx); e[1] = expf(x[1] - mx);
    e[2] = expf(x[2] - mx); e[3] = expf(x[3] - mx);
    s = (e[0] + e[1]) + (e[2] + e[3]);
  }
  #pragma unroll
  for (int o = 32; o > 0; o >>= 1) s += __shfl_down(s, o);
  if (lane == 0) ssum[wid] = s;
  __syncthreads();
  const float inv = 1.0f / (((ssum[0] + ssum[1]) + (ssum[2] + ssum[3])));
  if (act) {
    float4 o4 = make_float4(e[0] * inv, e[1] * inv, e[2] * inv, e[3] * inv);
    *(float4*)(out + (size_t)m * NANS + t * 4) = o4;
  }
}

// ---------------------------------------------------------------------------
extern "C" void kernel_launch(void* const* d_in, const int* in_sizes, int n_in,
                              void* d_out, int out_size, void* d_ws, size_t ws_size,
                              hipStream_t stream)
{
  const float* d1   = (const float*)d_in[0];
  const float* d2   = (const float*)d_in[1];
  const float* Wih1 = (const float*)d_in[2];
  const float* Whh1 = (const float*)d_in[3];
  const float* b1   = (const float*)d_in[4];
  const float* Wih2 = (const float*)d_in[5];
  const float* Whh2 = (const float*)d_in[6];
  const float* b2   = (const float*)d_in[7];
  const float* Wp1  = (const float*)d_in[8];
  const float* bp1  = (const float*)d_in[9];
  const float* Wp2  = (const float*)d_in[10];
  const float* bp2  = (const float*)d_in[11];
  float* out = (float*)d_out;

  // workspace layout (bytes)
  unsigned char* p = (unsigned char*)d_ws;
  unsigned short* gxb   = (unsigned short*)p;  p += 67108864;  // [T*64][4096]
  unsigned short* jb    = (unsigned short*)p;  p += 33554432;  // [8192][2048]
  unsigned short* Wb1   = (unsigned short*)p;  p += 16777216;  // [4096][2048]
  unsigned short* W2cat = (unsigned short*)p;  p += 16777216;  // [4096][2048]
  unsigned short* Whh1b = (unsigned short*)p;  p += 8388608;   // [4096][1024]
  unsigned short* lob   = (unsigned short*)p;  p += 16777216;  // [8192][1024]
  unsigned short* hidb  = (unsigned short*)p;  p += 4194304;   // [8192][256]
  unsigned short* Wp1t  = (unsigned short*)p;  p += 524288;    // [256][1024]
  unsigned short* Wp2t  = (unsigned short*)p;  p += 524288;    // [1024][256]
  unsigned short* H0    = (unsigned short*)p;  p += 262144;    // [64][2048]
  float*          c1    = (float*)p;           p += 262144;
  float*          c2    = (float*)p;           p += 262144;
  unsigned short* H1    = (unsigned short*)p;  p += 262144;
  if (ws_size < (size_t)(p - (unsigned char*)d_ws)) return;    // 158 MiB

  // ---- convert inputs/weights to bf16 ----
  concat_cast<<<16384, 256, 0, stream>>>(d1, d2, jb, 11, 16777216L);
  cast_bf16<<<8192, 256, 0, stream>>>(Wih1, Wb1, 8388608L);
  cast_bf16<<<4096, 256, 0, stream>>>(Whh1, Whh1b, 4194304L);
  concat_cast<<<8192, 256, 0, stream>>>(Wih2, Whh2, W2cat, 11, 8388608L);
  cvt_wp1<<<1024, 256, 0, stream>>>(Wp1, Wp1t);
  cvt_wp2<<<1024, 256, 0, stream>>>(Wp2, Wp2t);
  zero_f4<<<192, 256, 0, stream>>>((float4*)H0);   // H0 + c1 + c2 (contiguous)

  // ---- gx = joint @ Wih1^T + b1 (t-major permuted, bf16) ----
  mfma_gemm<1, 0, 1><<<dim3(32, 64), 256, 0, stream>>>(
      jb, Wb1, b1, gxb, MALL, G4, DIN, G4, G4);

  // ---- recurrent loop, ping-pong h buffers ----
  for (int t = 0; t < TT; t++) {
    unsigned short* hp = (t & 1) ? H1 : H0;
    unsigned short* hc = (t & 1) ? H0 : H1;
    lstm_stepA<<<256, 256, 0, stream>>>(hp, Whh1b, gxb, t, hc, c1);
    lstm_stepB<<<256, 256, 0, stream>>>(hp, hc, W2cat, b2, t, c2, lob);
  }

  // ---- predict MLP + softmax ----
  mfma_gemm<1, 1, 0><<<dim3(2, 64), 256, 0, stream>>>(
      lob, Wp1t, bp1, hidb, MALL, 256, 1024, 256, 256);
  mfma_gemm<0, 0, 0><<<dim3(8, 64), 256, 0, stream>>>(
      hidb, Wp2t, bp2, out, MALL, 1024, 256, NANS, NANS);
  softmax_k<<<MALL, 256, 0, stream>>>(out);
}